// Round 4
// baseline (122.449 us; speedup 1.0000x reference)
//
#include <hip/hip_runtime.h>
#include <hip/hip_bf16.h>

// CapsuleLayer dynamic routing, MI355X. fp32 in/out.
// C=10, B=128, N=1152, IN=8, OUT=16, 3 routing iters.
//
// v12 (round 14): G=2 @ 1024 threads — halve W cache traffic at full occupancy.
//   r13 (v11): no spills, 62% occupancy, but only -7% vs v8 at half v8's
//   occupancy -> not purely latency-bound. Arithmetic: W streams 590 KB/block
//   x 1280 blocks = 755 MB / 42.5 us = 17.8 TB/s = ~60% of per-CU L1 path
//   (39 B/cyc of ~64) and ~52% of L2. The lever is bytes, not waves.
//   v12: G=2 shares each W line across 2 batches (W traffic 755 -> 378 MB)
//   and 1024-thread blocks keep occupancy: P storage is 36.9 KB per batch
//   REGARDLESS of thread count, so ldsP = 73.7 KB, total 78 KB -> 2 blocks/CU
//   = 32 waves/CU (HW max). Each wave owns 72 rows = 4.5 passes of 16; the
//   half pass is predicated on rsub<8 (quad-uniform -> shfl-safe). W loads
//   split in two i-halves (4 float4 live at a time) to keep natural VGPR
//   ~55-60 < 64 (the 2-blocks/CU VGPR cliff). fp32 math unchanged; P storage
//   bf16 (absmax 0.0059, threshold 0.0172). No forced min-waves (v10 lesson).
//
// Structure: 1024 thr = 16 waves, one block per (c, b-pair), 640 blocks.
//   Lane l: o-quad q=l&3 (owns o=q*4..+3), row-sub rsub=l>>2; wave w covers
//   rows [w*72,(w+1)*72). W float4 load = 16 rows x 64 B fully-consumed lines.
//   Logit state eliminated: logit = dot(accum-out, P) recomputed per iter.
//   Unnormalized softmax (|logit| <~ 30, fp32-safe). ldsP slots thread-private
//   (no barrier in P pipeline; lgkmcnt orders same-thread RAW); ds b64 lane
//   pattern = 2 lanes/bank/phase = free (m136, v11 measured 0 conflicts).
//   XCD-chunked swizzle: 640 = 8 x 80, per-XCD W ws ~1.2 MB (L2-fit).

constexpr int C = 10, B = 128, N = 1152, IN = 8, OUT = 16;
constexpr int THREADS = 1024;
constexpr int NW = THREADS / 64;          // 16 waves
constexpr int G = 2;                      // batches per block
constexpr int ROWS_W = N / NW;            // 72 rows per wave
constexpr int NBLK = C * (B / G);         // 640
constexpr int NXCD = 8;
constexpr int CHUNK = NBLK / NXCD;        // 80 (640 % 8 == 0: bijective)

__device__ __forceinline__ unsigned packbf(float a, float b) {
    __hip_bfloat162 h = __float22bfloat162_rn(float2{a, b});  // RNE
    return *(unsigned*)&h;
}
__device__ __forceinline__ float bflo(unsigned u) { return __uint_as_float(u << 16); }
__device__ __forceinline__ float bfhi(unsigned u) { return __uint_as_float(u & 0xffff0000u); }

__global__ __launch_bounds__(THREADS)
void caps_route(const float* __restrict__ Xf, const float* __restrict__ Wf,
                float* __restrict__ Of) {
    // P packed by row: slot ((g*N+n)<<2)|q, .x=bf16x2(P0,P1), .y=bf16x2(P2,P3)
    __shared__ uint2 ldsP[G * N * 4];                  // 73,728 B
    __shared__ float lds_s[2][G][NW][OUT];             // parity-buffered wave sums
    __shared__ float lds_sum[2][G][NW];                // parity-buffered denoms

    const int t = threadIdx.x;
    const int l = t & 63;
    const int wid = t >> 6;
    const int q = l & 3;        // o-quad: owns o = q*4 .. q*4+3
    const int rsub = l >> 2;    // row-sub within a pass (0..15)

    // XCD-chunked swizzle: physical bid%8 -> XCD (round-robin dispatch).
    // XCD x gets logical [x*80, x*80+80) -> ~1.25 distinct c resident.
    const int bid = blockIdx.x;
    const int blk = (bid & (NXCD - 1)) * CHUNK + (bid >> 3);
    const int c = blk >> 6;     // 64 consecutive logical blocks share c
    const int b0 = (blk & 63) * G;

    // ---- priors: P[g][n][o] = sum_i x[b0+g,n,i] * W[c,n,i,o]
    // (fp32 acc, bf16 store). Fused iter-0 sums (logits 0 -> uniform softmax).
    // 4.5 passes: p=0..4, p==4 active only for rsub<8 (quad-uniform).
    float s40[G][4] = {{0.f, 0.f, 0.f, 0.f}, {0.f, 0.f, 0.f, 0.f}};
    const int nbase = wid * ROWS_W + rsub;
    #pragma unroll 1
    for (int p = 0; p < 5; ++p) {
        if ((p < 4) | (rsub < 8)) {
            const int n = nbase + p * 16;
            const float4* wr = (const float4*)(Wf + (size_t)(c * N + n) * (IN * OUT)) + q;
            const float4* x0 = (const float4*)(Xf + (size_t)((b0 + 0) * N + n) * IN);
            const float4* x1 = (const float4*)(Xf + (size_t)((b0 + 1) * N + n) * IN);
            const float4 xa0 = x0[0], xc0 = x0[1];
            const float4 xa1 = x1[0], xc1 = x1[1];
            // i = 0..3
            float4 u0 = wr[0], u1 = wr[4], u2 = wr[8], u3 = wr[12];
            float a0 = xa0.x * u0.x, a1 = xa0.x * u0.y, a2 = xa0.x * u0.z, a3 = xa0.x * u0.w;
            float b0v = xa1.x * u0.x, b1v = xa1.x * u0.y, b2v = xa1.x * u0.z, b3v = xa1.x * u0.w;
            a0 = fmaf(xa0.y, u1.x, a0); a1 = fmaf(xa0.y, u1.y, a1);
            a2 = fmaf(xa0.y, u1.z, a2); a3 = fmaf(xa0.y, u1.w, a3);
            b0v = fmaf(xa1.y, u1.x, b0v); b1v = fmaf(xa1.y, u1.y, b1v);
            b2v = fmaf(xa1.y, u1.z, b2v); b3v = fmaf(xa1.y, u1.w, b3v);
            a0 = fmaf(xa0.z, u2.x, a0); a1 = fmaf(xa0.z, u2.y, a1);
            a2 = fmaf(xa0.z, u2.z, a2); a3 = fmaf(xa0.z, u2.w, a3);
            b0v = fmaf(xa1.z, u2.x, b0v); b1v = fmaf(xa1.z, u2.y, b1v);
            b2v = fmaf(xa1.z, u2.z, b2v); b3v = fmaf(xa1.z, u2.w, b3v);
            a0 = fmaf(xa0.w, u3.x, a0); a1 = fmaf(xa0.w, u3.y, a1);
            a2 = fmaf(xa0.w, u3.z, a2); a3 = fmaf(xa0.w, u3.w, a3);
            b0v = fmaf(xa1.w, u3.x, b0v); b1v = fmaf(xa1.w, u3.y, b1v);
            b2v = fmaf(xa1.w, u3.z, b2v); b3v = fmaf(xa1.w, u3.w, b3v);
            // i = 4..7 (reuse u regs)
            u0 = wr[16]; u1 = wr[20]; u2 = wr[24]; u3 = wr[28];
            a0 = fmaf(xc0.x, u0.x, a0); a1 = fmaf(xc0.x, u0.y, a1);
            a2 = fmaf(xc0.x, u0.z, a2); a3 = fmaf(xc0.x, u0.w, a3);
            b0v = fmaf(xc1.x, u0.x, b0v); b1v = fmaf(xc1.x, u0.y, b1v);
            b2v = fmaf(xc1.x, u0.z, b2v); b3v = fmaf(xc1.x, u0.w, b3v);
            a0 = fmaf(xc0.y, u1.x, a0); a1 = fmaf(xc0.y, u1.y, a1);
            a2 = fmaf(xc0.y, u1.z, a2); a3 = fmaf(xc0.y, u1.w, a3);
            b0v = fmaf(xc1.y, u1.x, b0v); b1v = fmaf(xc1.y, u1.y, b1v);
            b2v = fmaf(xc1.y, u1.z, b2v); b3v = fmaf(xc1.y, u1.w, b3v);
            a0 = fmaf(xc0.z, u2.x, a0); a1 = fmaf(xc0.z, u2.y, a1);
            a2 = fmaf(xc0.z, u2.z, a2); a3 = fmaf(xc0.z, u2.w, a3);
            b0v = fmaf(xc1.z, u2.x, b0v); b1v = fmaf(xc1.z, u2.y, b1v);
            b2v = fmaf(xc1.z, u2.z, b2v); b3v = fmaf(xc1.z, u2.w, b3v);
            a0 = fmaf(xc0.w, u3.x, a0); a1 = fmaf(xc0.w, u3.y, a1);
            a2 = fmaf(xc0.w, u3.z, a2); a3 = fmaf(xc0.w, u3.w, a3);
            b0v = fmaf(xc1.w, u3.x, b0v); b1v = fmaf(xc1.w, u3.y, b1v);
            b2v = fmaf(xc1.w, u3.z, b2v); b3v = fmaf(xc1.w, u3.w, b3v);

            s40[0][0] += a0;  s40[0][1] += a1;  s40[0][2] += a2;  s40[0][3] += a3;
            s40[1][0] += b0v; s40[1][1] += b1v; s40[1][2] += b2v; s40[1][3] += b3v;
            ldsP[(n << 2) | q]       = uint2{packbf(a0, a1), packbf(a2, a3)};
            ldsP[((N + n) << 2) | q] = uint2{packbf(b0v, b1v), packbf(b2v, b3v)};
        }
    }

    // accumulated output quad-slice (fp32); logit[p] == dot(oa_full16, P[p])
    float oa[G][4] = {{0.f, 0.f, 0.f, 0.f}, {0.f, 0.f, 0.f, 0.f}};

    // ---- dynamic routing ----
    for (int it = 0; it < 3; ++it) {
        const int pb = it & 1;
        float s4[G][4];
        float ssum[G];
        if (it == 0) {
            const float rows = (rsub < 8) ? 5.f : 4.f;  // rows this thread summed
            #pragma unroll
            for (int g = 0; g < G; ++g) {
                ssum[g] = rows;
                #pragma unroll
                for (int k = 0; k < 4; ++k) s4[g][k] = s40[g][k];
            }
        } else {
            #pragma unroll
            for (int g = 0; g < G; ++g) {
                ssum[g] = 0.f;
                #pragma unroll
                for (int k = 0; k < 4; ++k) s4[g][k] = 0.f;
            }
            #pragma unroll
            for (int p = 0; p < 5; ++p) {
                if ((p < 4) | (rsub < 8)) {     // quad-uniform: shfl-safe
                    const int n = nbase + p * 16;
                    #pragma unroll
                    for (int g = 0; g < G; ++g) {
                        const uint2 u = ldsP[((g * N + n) << 2) | q];
                        const float p0 = bflo(u.x), p1 = bfhi(u.x);
                        const float p2 = bflo(u.y), p3 = bfhi(u.y);
                        // logit = dot(out_accum, P) via quad butterfly
                        float d = oa[g][0] * p0;
                        d = fmaf(oa[g][1], p1, d);
                        d = fmaf(oa[g][2], p2, d);
                        d = fmaf(oa[g][3], p3, d);
                        d += __shfl_xor(d, 1, 64);
                        d += __shfl_xor(d, 2, 64);
                        const float e = __expf(d);      // replicated across quad
                        ssum[g] += e;
                        s4[g][0] = fmaf(e, p0, s4[g][0]);
                        s4[g][1] = fmaf(e, p1, s4[g][1]);
                        s4[g][2] = fmaf(e, p2, s4[g][2]);
                        s4[g][3] = fmaf(e, p3, s4[g][3]);
                    }
                }
            }
        }
        // reduce across the 16 row-subs of the wave (masks 4..32; quad bits
        // 0,1 carry replicas (ssum) / distinct o (s4) -> not summed)
        #pragma unroll
        for (int m = 4; m < 64; m <<= 1) {
            #pragma unroll
            for (int g = 0; g < G; ++g) {
                ssum[g] += __shfl_xor(ssum[g], m, 64);
                #pragma unroll
                for (int k = 0; k < 4; ++k) s4[g][k] += __shfl_xor(s4[g][k], m, 64);
            }
        }
        if (l < 4) {  // lane l == quad q: owns o = l*4..l*4+3
            #pragma unroll
            for (int g = 0; g < G; ++g)
                #pragma unroll
                for (int k = 0; k < 4; ++k) lds_s[pb][g][wid][l * 4 + k] = s4[g][k];
        }
        if (l == 0) {
            #pragma unroll
            for (int g = 0; g < G; ++g) lds_sum[pb][g][wid] = ssum[g];
        }
        __syncthreads();

        // all-thread redundant combine + squash (each thread: its own o-quad).
        // lds_s reads: 4 distinct 16B addrs/wave -> 16-lane broadcast, free.
        float ov[G][4];
        #pragma unroll
        for (int g = 0; g < G; ++g) {
            float a0 = 0.f, a1 = 0.f, a2 = 0.f, a3 = 0.f, S = 0.f;
            #pragma unroll
            for (int w = 0; w < NW; ++w) {
                const float4 v = *(const float4*)&lds_s[pb][g][w][q * 4];
                a0 += v.x; a1 += v.y; a2 += v.z; a3 += v.w;
                S += lds_sum[pb][g][w];
            }
            const float inv = 1.f / S;
            const float s0 = a0 * inv, s1 = a1 * inv;
            const float s2 = a2 * inv, s3 = a3 * inv;
            float r = s0 * s0 + s1 * s1 + s2 * s2 + s3 * s3;
            r += __shfl_xor(r, 1, 64);
            r += __shfl_xor(r, 2, 64);
            const float sc = r / ((1.f + r) * sqrtf(r + 1e-8f));
            ov[g][0] = s0 * sc; ov[g][1] = s1 * sc;
            ov[g][2] = s2 * sc; ov[g][3] = s3 * sc;
        }
        if (it < 2) {
            #pragma unroll
            for (int g = 0; g < G; ++g)
                #pragma unroll
                for (int k = 0; k < 4; ++k) oa[g][k] += ov[g][k];
        } else if (t < 4) {  // wid==0, rsub==0, q==t: write final outputs
            #pragma unroll
            for (int g = 0; g < G; ++g)
                #pragma unroll
                for (int k = 0; k < 4; ++k)
                    Of[((size_t)c * B + b0 + g) * OUT + q * 4 + k] = ov[g][k];
        }
    }
}

extern "C" void kernel_launch(void* const* d_in, const int* in_sizes, int n_in,
                              void* d_out, int out_size, void* d_ws, size_t ws_size,
                              hipStream_t stream) {
    const float* X = (const float*)d_in[0];   // [B,N,IN] fp32
    const float* W = (const float*)d_in[1];   // [C,N,IN,OUT] fp32
    float* O = (float*)d_out;                 // [C,B,OUT] fp32
    hipLaunchKernelGGL(caps_route, dim3(NBLK), dim3(THREADS), 0, stream, X, W, O);
}

// Round 5
// 94.361 us; speedup vs baseline: 1.2977x; 1.2977x over previous
//
#include <hip/hip_runtime.h>
#include <hip/hip_bf16.h>

// CapsuleLayer dynamic routing, MI355X. fp32 in/out.
// C=10, B=128, N=1152, IN=8, OUT=16, 3 routing iters.
//
// v13 (round 15): G=2 HYBRID P storage — LDS batch + register batch.
//   LDS identity: P-in-LDS caps at 160/36.9 ~= 4 batches/CU however blocked
//   (v11: 4 blk x G=1, 32 w; v8: 2 blk x G=2, 16 w). v12 (1024t) showed 1024-
//   thread blocks don't co-schedule -> avoid. Escape: batch g1's P lives in
//   18 VGPRs/thread (9 x uint2 bf16x2, statically indexed). Block LDS = one
//   batch (36.9 KB) + 1.3 KB combine buf -> 4 blocks/CU AND G=2 halves W
//   traffic 755->378 MB. Priors fully unrolled (static Pr[p] writes; dynamic
//   index would demote to scratch) with sched_barrier(0) between passes to
//   stop cross-pass W-load hoisting (the r5-r9 ~300-reg balloon); v11 proved
//   per-pass MLP=8 suffices at 32 w/CU. W,X loaded in i-halves to keep peak
//   ~60 VGPR. Parity double-buffer replaced by 2nd barrier (combine buf
//   [G][8][20] f32 = 1280 B). g1 routing reads are pure VALU unpacks (DS-pipe
//   relief). Falsifier: ~42 us at occ>=45 + no spills -> bytes not binding;
//   floor is DS/shfl serialization -> attack butterfly next.
//
// Structure: 512 thr = 8 waves, one block per (c, b-pair), 640 blocks.
//   Lane l: o-quad q=l&3 (owns o=q*4..+3), row-sub rsub=l>>2; wave w covers
//   rows [w*144,(w+1)*144) in 9 passes of 16. W float4 load = 16 rows x 64 B
//   fully-consumed lines. fp32 accumulation; only P storage is bf16 (absmax
//   0.0059, threshold 0.0172). Logit state eliminated: logit = dot(oa, P)
//   recomputed per iter. Unnormalized softmax (|logit| <~30, fp32-safe).
//   ldsP slots thread-private (lgkmcnt orders same-thread RAW, no barrier);
//   8B lane stride = 2-way bank aliasing = free (m136). XCD-chunked swizzle:
//   640 = 8 x 80 bijective, per-XCD W ws ~1.2 MB (L2-fit).

constexpr int C = 10, B = 128, N = 1152, IN = 8, OUT = 16;
constexpr int THREADS = 512;
constexpr int NW = THREADS / 64;          // 8 waves
constexpr int G = 2;                      // batches per block
constexpr int PASSES = N / (NW * 16);     // 9
constexpr int NBLK = C * (B / G);         // 640
constexpr int NXCD = 8;
constexpr int CHUNK = NBLK / NXCD;        // 80 (640 % 8 == 0: bijective)

__device__ __forceinline__ unsigned packbf(float a, float b) {
    __hip_bfloat162 h = __float22bfloat162_rn(float2{a, b});  // RNE
    return *(unsigned*)&h;
}
__device__ __forceinline__ float bflo(unsigned u) { return __uint_as_float(u << 16); }
__device__ __forceinline__ float bfhi(unsigned u) { return __uint_as_float(u & 0xffff0000u); }

__global__ __launch_bounds__(THREADS)
void caps_route(const float* __restrict__ Xf, const float* __restrict__ Wf,
                float* __restrict__ Of) {
    // g0's P: thread-private slots, .x=bf16x2(P0,P1), .y=bf16x2(P2,P3)
    __shared__ uint2 ldsP[PASSES * THREADS];           // 36,864 B
    // combine buffer: [g][w][0..15]=s4 by o, [16]=ssum, [17..19] pad
    __shared__ float lds_c[G][NW][20];                 // 1,280 B

    const int t = threadIdx.x;
    const int l = t & 63;
    const int wid = t >> 6;
    const int q = l & 3;        // o-quad: owns o = q*4 .. q*4+3
    const int rsub = l >> 2;    // row-sub within a pass (0..15)

    // XCD-chunked swizzle: physical bid%8 -> XCD (round-robin dispatch).
    const int bid = blockIdx.x;
    const int blk = (bid & (NXCD - 1)) * CHUNK + (bid >> 3);
    const int c = blk >> 6;     // 64 consecutive logical blocks share c
    const int b0 = (blk & 63) * G;

    // ---- priors: P[g][n][o] = sum_i x[b0+g,n,i] * W[c,n,i,o]
    // g0 -> LDS, g1 -> registers (bf16x2, static index). Fully unrolled with
    // sched_barrier(0) pass separators (prevents W-load hoist balloon).
    uint2 Pr[PASSES];
    const int nbase = wid * (16 * PASSES) + rsub;
    #pragma unroll
    for (int p = 0; p < PASSES; ++p) {
        const int n = nbase + p * 16;
        const float4* wr = (const float4*)(Wf + (size_t)(c * N + n) * (IN * OUT)) + q;
        const float4* x0 = (const float4*)(Xf + (size_t)((b0 + 0) * N + n) * IN);
        const float4* x1 = (const float4*)(Xf + (size_t)((b0 + 1) * N + n) * IN);
        float a0, a1, a2, a3, e0, e1, e2, e3;
        {   // i = 0..3
            const float4 xa0 = x0[0], xa1 = x1[0];
            const float4 u0 = wr[0], u1 = wr[4], u2 = wr[8], u3 = wr[12];
            a0 = xa0.x * u0.x; a1 = xa0.x * u0.y; a2 = xa0.x * u0.z; a3 = xa0.x * u0.w;
            e0 = xa1.x * u0.x; e1 = xa1.x * u0.y; e2 = xa1.x * u0.z; e3 = xa1.x * u0.w;
            a0 = fmaf(xa0.y, u1.x, a0); a1 = fmaf(xa0.y, u1.y, a1);
            a2 = fmaf(xa0.y, u1.z, a2); a3 = fmaf(xa0.y, u1.w, a3);
            e0 = fmaf(xa1.y, u1.x, e0); e1 = fmaf(xa1.y, u1.y, e1);
            e2 = fmaf(xa1.y, u1.z, e2); e3 = fmaf(xa1.y, u1.w, e3);
            a0 = fmaf(xa0.z, u2.x, a0); a1 = fmaf(xa0.z, u2.y, a1);
            a2 = fmaf(xa0.z, u2.z, a2); a3 = fmaf(xa0.z, u2.w, a3);
            e0 = fmaf(xa1.z, u2.x, e0); e1 = fmaf(xa1.z, u2.y, e1);
            e2 = fmaf(xa1.z, u2.z, e2); e3 = fmaf(xa1.z, u2.w, e3);
            a0 = fmaf(xa0.w, u3.x, a0); a1 = fmaf(xa0.w, u3.y, a1);
            a2 = fmaf(xa0.w, u3.z, a2); a3 = fmaf(xa0.w, u3.w, a3);
            e0 = fmaf(xa1.w, u3.x, e0); e1 = fmaf(xa1.w, u3.y, e1);
            e2 = fmaf(xa1.w, u3.z, e2); e3 = fmaf(xa1.w, u3.w, e3);
        }
        {   // i = 4..7
            const float4 xc0 = x0[1], xc1 = x1[1];
            const float4 u0 = wr[16], u1 = wr[20], u2 = wr[24], u3 = wr[28];
            a0 = fmaf(xc0.x, u0.x, a0); a1 = fmaf(xc0.x, u0.y, a1);
            a2 = fmaf(xc0.x, u0.z, a2); a3 = fmaf(xc0.x, u0.w, a3);
            e0 = fmaf(xc1.x, u0.x, e0); e1 = fmaf(xc1.x, u0.y, e1);
            e2 = fmaf(xc1.x, u0.z, e2); e3 = fmaf(xc1.x, u0.w, e3);
            a0 = fmaf(xc0.y, u1.x, a0); a1 = fmaf(xc0.y, u1.y, a1);
            a2 = fmaf(xc0.y, u1.z, a2); a3 = fmaf(xc0.y, u1.w, a3);
            e0 = fmaf(xc1.y, u1.x, e0); e1 = fmaf(xc1.y, u1.y, e1);
            e2 = fmaf(xc1.y, u1.z, e2); e3 = fmaf(xc1.y, u1.w, e3);
            a0 = fmaf(xc0.z, u2.x, a0); a1 = fmaf(xc0.z, u2.y, a1);
            a2 = fmaf(xc0.z, u2.z, a2); a3 = fmaf(xc0.z, u2.w, a3);
            e0 = fmaf(xc1.z, u2.x, e0); e1 = fmaf(xc1.z, u2.y, e1);
            e2 = fmaf(xc1.z, u2.z, e2); e3 = fmaf(xc1.z, u2.w, e3);
            a0 = fmaf(xc0.w, u3.x, a0); a1 = fmaf(xc0.w, u3.y, a1);
            a2 = fmaf(xc0.w, u3.z, a2); a3 = fmaf(xc0.w, u3.w, a3);
            e0 = fmaf(xc1.w, u3.x, e0); e1 = fmaf(xc1.w, u3.y, e1);
            e2 = fmaf(xc1.w, u3.z, e2); e3 = fmaf(xc1.w, u3.w, e3);
        }
        ldsP[p * THREADS + t] = uint2{packbf(a0, a1), packbf(a2, a3)};
        Pr[p] = uint2{packbf(e0, e1), packbf(e2, e3)};
        __builtin_amdgcn_sched_barrier(0);   // no cross-pass load hoisting
    }

    // accumulated output quad-slice (fp32); logit[p] == dot(oa_full16, P[p])
    float oa[G][4] = {{0.f, 0.f, 0.f, 0.f}, {0.f, 0.f, 0.f, 0.f}};

    // ---- dynamic routing ----
    for (int it = 0; it < 3; ++it) {
        float s4[G][4];
        float ssum[G];
        if (it == 0) {
            // logits all 0 -> e = 1: plain sums over this thread's 9 rows
            ssum[0] = ssum[1] = (float)PASSES;
            #pragma unroll
            for (int g = 0; g < G; ++g)
                #pragma unroll
                for (int k = 0; k < 4; ++k) s4[g][k] = 0.f;
            #pragma unroll
            for (int p = 0; p < PASSES; ++p) {
                const uint2 u = ldsP[p * THREADS + t];
                s4[0][0] += bflo(u.x); s4[0][1] += bfhi(u.x);
                s4[0][2] += bflo(u.y); s4[0][3] += bfhi(u.y);
                const uint2 v = Pr[p];
                s4[1][0] += bflo(v.x); s4[1][1] += bfhi(v.x);
                s4[1][2] += bflo(v.y); s4[1][3] += bfhi(v.y);
            }
        } else {
            ssum[0] = ssum[1] = 0.f;
            #pragma unroll
            for (int g = 0; g < G; ++g)
                #pragma unroll
                for (int k = 0; k < 4; ++k) s4[g][k] = 0.f;
            #pragma unroll
            for (int p = 0; p < PASSES; ++p) {
                {   // g0 from LDS
                    const uint2 u = ldsP[p * THREADS + t];
                    const float p0 = bflo(u.x), p1 = bfhi(u.x);
                    const float p2 = bflo(u.y), p3 = bfhi(u.y);
                    float d = oa[0][0] * p0;
                    d = fmaf(oa[0][1], p1, d);
                    d = fmaf(oa[0][2], p2, d);
                    d = fmaf(oa[0][3], p3, d);
                    d += __shfl_xor(d, 1, 64);
                    d += __shfl_xor(d, 2, 64);
                    const float e = __expf(d);      // replicated across quad
                    ssum[0] += e;
                    s4[0][0] = fmaf(e, p0, s4[0][0]);
                    s4[0][1] = fmaf(e, p1, s4[0][1]);
                    s4[0][2] = fmaf(e, p2, s4[0][2]);
                    s4[0][3] = fmaf(e, p3, s4[0][3]);
                }
                {   // g1 from registers (pure VALU)
                    const uint2 v = Pr[p];
                    const float p0 = bflo(v.x), p1 = bfhi(v.x);
                    const float p2 = bflo(v.y), p3 = bfhi(v.y);
                    float d = oa[1][0] * p0;
                    d = fmaf(oa[1][1], p1, d);
                    d = fmaf(oa[1][2], p2, d);
                    d = fmaf(oa[1][3], p3, d);
                    d += __shfl_xor(d, 1, 64);
                    d += __shfl_xor(d, 2, 64);
                    const float e = __expf(d);
                    ssum[1] += e;
                    s4[1][0] = fmaf(e, p0, s4[1][0]);
                    s4[1][1] = fmaf(e, p1, s4[1][1]);
                    s4[1][2] = fmaf(e, p2, s4[1][2]);
                    s4[1][3] = fmaf(e, p3, s4[1][3]);
                }
            }
        }
        // reduce across the 16 row-subs of the wave (masks 4..32; quad bits
        // 0,1 carry replicas (ssum) / distinct o (s4) -> not summed).
        // 10 independent chains -> shfl latency overlapped by ILP.
        #pragma unroll
        for (int m = 4; m < 64; m <<= 1) {
            #pragma unroll
            for (int g = 0; g < G; ++g) {
                ssum[g] += __shfl_xor(ssum[g], m, 64);
                #pragma unroll
                for (int k = 0; k < 4; ++k) s4[g][k] += __shfl_xor(s4[g][k], m, 64);
            }
        }
        if (l < 4) {  // lane l == quad q: owns o = l*4..l*4+3
            #pragma unroll
            for (int g = 0; g < G; ++g)
                #pragma unroll
                for (int k = 0; k < 4; ++k) lds_c[g][wid][l * 4 + k] = s4[g][k];
        }
        if (l == 0) {
            #pragma unroll
            for (int g = 0; g < G; ++g) lds_c[g][wid][16] = ssum[g];
        }
        __syncthreads();   // A: combine buffer ready

        // all-thread redundant combine + squash (each thread: its own o-quad).
        // lds_c reads: 4 distinct 16B addrs/wave -> 16-lane broadcast, free.
        float ov[G][4];
        #pragma unroll
        for (int g = 0; g < G; ++g) {
            float a0 = 0.f, a1 = 0.f, a2 = 0.f, a3 = 0.f, S = 0.f;
            #pragma unroll
            for (int w = 0; w < NW; ++w) {
                const float4 v = *(const float4*)&lds_c[g][w][q * 4];
                a0 += v.x; a1 += v.y; a2 += v.z; a3 += v.w;
                S += lds_c[g][w][16];
            }
            const float inv = 1.f / S;
            const float s0 = a0 * inv, s1 = a1 * inv;
            const float s2 = a2 * inv, s3 = a3 * inv;
            float r = s0 * s0 + s1 * s1 + s2 * s2 + s3 * s3;
            r += __shfl_xor(r, 1, 64);
            r += __shfl_xor(r, 2, 64);
            const float sc = r / ((1.f + r) * sqrtf(r + 1e-8f));
            ov[g][0] = s0 * sc; ov[g][1] = s1 * sc;
            ov[g][2] = s2 * sc; ov[g][3] = s3 * sc;
        }
        if (it < 2) {
            __syncthreads();   // B: combine reads done before next write
            #pragma unroll
            for (int g = 0; g < G; ++g)
                #pragma unroll
                for (int k = 0; k < 4; ++k) oa[g][k] += ov[g][k];
        } else if (t < 4) {  // wid==0, rsub==0, q==t: write final outputs
            #pragma unroll
            for (int g = 0; g < G; ++g)
                #pragma unroll
                for (int k = 0; k < 4; ++k)
                    Of[((size_t)c * B + b0 + g) * OUT + q * 4 + k] = ov[g][k];
        }
    }
}

extern "C" void kernel_launch(void* const* d_in, const int* in_sizes, int n_in,
                              void* d_out, int out_size, void* d_ws, size_t ws_size,
                              hipStream_t stream) {
    const float* X = (const float*)d_in[0];   // [B,N,IN] fp32
    const float* W = (const float*)d_in[1];   // [C,N,IN,OUT] fp32
    float* O = (float*)d_out;                 // [C,B,OUT] fp32
    hipLaunchKernelGGL(caps_route, dim3(NBLK), dim3(THREADS), 0, stream, X, W, O);
}